// Round 13
// baseline (814.275 us; speedup 1.0000x reference)
//
#include <hip/hip_runtime.h>

#define T_STEPS 512
#define B_ENV   256
#define D_IN    64
#define H_DIM   128

// ---- MFMA types (clang builtins use __fp16 vectors on gfx950) ----
typedef __fp16 g2 __attribute__((ext_vector_type(2)));
typedef __fp16 g8 __attribute__((ext_vector_type(8)));
typedef float  f4v __attribute__((ext_vector_type(4)));
// ---- proj-kernel types (dot2 path) ----
typedef _Float16 h2v __attribute__((ext_vector_type(2)));
typedef _Float16 h8v __attribute__((ext_vector_type(8)));

__device__ __forceinline__ g2 pack16g(float a, float b) {
#if __has_builtin(__builtin_amdgcn_cvt_pkrtz)
    return __builtin_amdgcn_cvt_pkrtz(a, b);
#else
    g2 p; p.x = (__fp16)a; p.y = (__fp16)b; return p;
#endif
}
__device__ __forceinline__ h2v pack16(float a, float b) {
    union { g2 r; h2v h; } u; u.r = pack16g(a, b); return u.h;
}

__device__ __forceinline__ float dot2(h2v a, h2v b, float c) {
#if __has_builtin(__builtin_amdgcn_fdot2)
    return __builtin_amdgcn_fdot2(a, b, c, false);
#else
    return c + (float)a.x * (float)b.x + (float)a.y * (float)b.y;
#endif
}

__device__ __forceinline__ f4v mfma16(g8 a, g8 b, f4v c) {
    return __builtin_amdgcn_mfma_f32_16x16x32_f16(a, b, c, 0, 0, 0);
}

__device__ __forceinline__ float fast_rcp(float x) {
#if __has_builtin(__builtin_amdgcn_rcpf)
    return __builtin_amdgcn_rcpf(x);
#else
    return 1.0f / x;
#endif
}
__device__ __forceinline__ float sigm(float x)   { return fast_rcp(1.0f + __expf(-x)); }
__device__ __forceinline__ float tanh_f(float x) { float e = __expf(2.0f * x); return 1.0f - 2.0f * fast_rcp(e + 1.0f); }

// Barrier draining LDS ops only — global loads/stores stay in flight.
__device__ __forceinline__ void sync_lds() {
    asm volatile("s_waitcnt lgkmcnt(0)" ::: "memory");
    __builtin_amdgcn_s_barrier();
    asm volatile("" ::: "memory");
}

// One-wave async global->LDS: 64 lanes x 4B = 256B (one full x row).
__device__ __forceinline__ void async_load_row(const float* gsrc, float* ldst) {
    __builtin_amdgcn_global_load_lds(
        (const __attribute__((address_space(1))) unsigned int*)gsrc,
        (__attribute__((address_space(3))) unsigned int*)ldst, 4, 0, 0);
}

// MFMA scan: one block per env, 512 threads = 8 waves, 2 waves/SIMD
// (VGPR budget 256 — room for 96 regs of A-frags + 16 bias + temps).
// Wave w owns 64 gate rows: gate g=w>>1 (0:i 1:f 2:g 3:o), j-half w&1.
//   A-frags (per lane, preloaded once, f16): W_hh 4 Mtiles x 4 Kstrips,
//   W_ih 4 x 2. Per step: B-frags = h / x from LDS with ALL 16 cols
//   replicated (each lane's C output is then the true gate value for its
//   rows -> epilogue fully parallel, bit-identical across col lanes).
//   24 MFMA accumulate Whh.h + Wih.x + bias (acc init). Activation
//   (wave-uniform type) -> col-0 lanes write g_lds[4][128] -> barrier ->
//   tid<128 cell update (c in regs; done-mask folded: h16 pre-scaled by
//   smask[t+1], c scaled by smask[t]) -> h16[wb] + hs store -> barrier.
// Wave 0 drives the x ring (global_load_lds x_{t+3}; f32->f16 convert of
// x_{t+1}; counted vmcnt(2): retires only L(t+2), never waits on stores).
__global__ __launch_bounds__(512, 1) __attribute__((amdgpu_waves_per_eu(2, 2)))
void ppo_lstm_scan(const float* __restrict__ x,      // [T,B,D]
                   const float* __restrict__ done,   // [T,B]
                   const float* __restrict__ h0,     // [B,H]
                   const float* __restrict__ c0,     // [B,H]
                   const float* __restrict__ W_ih,   // [4H,D]
                   const float* __restrict__ b_ih,   // [4H]
                   const float* __restrict__ W_hh,   // [4H,H]
                   const float* __restrict__ b_hh,   // [4H]
                   float* __restrict__ hs)           // [T,B,H] = d_out (raw h)
{
    const int tid  = threadIdx.x;
    const int b    = blockIdx.x;
    const int lane = tid & 63;
    const int wid  = tid >> 6;
    const int colg = lane >> 4;        // 0..3 (k-group / row-subgroup)
    const int rml  = lane & 15;        // row within M-tile
    const int g    = wid >> 1;         // gate index (wave-uniform)
    const int jb   = (wid & 1) * 64;   // j base of this wave
    const int rowbase = g * H_DIM + jb;

    __shared__ __fp16 h16[2][H_DIM];       // h f16, dbuf (pre-masked)
    __shared__ __fp16 x16[2][D_IN];        // x f16, dbuf
    __shared__ float  g_lds[4][H_DIM];     // activated gates [gate][j]
    __shared__ float  smask[T_STEPS];      // 1-done
    __shared__ float  xring[4][D_IN];      // x f32 ring

    // ---- one-time: A-fragments + bias -> registers ----
    union FR { g2 p[4]; g8 v; };
    g8 wa[4][4];   // [Mtile][Kstrip] of W_hh rows
    g8 xa[4][2];   // [Mtile][Kstrip] of W_ih rows
    float bias[16];
    #pragma unroll
    for (int mt = 0; mt < 4; ++mt) {
        const int row = rowbase + mt * 16 + rml;     // A row = lane&15
        #pragma unroll
        for (int ks = 0; ks < 4; ++ks) {
            const float* p = W_hh + (size_t)row * H_DIM + ks * 32 + colg * 8;
            FR u;
            #pragma unroll
            for (int c = 0; c < 4; ++c) u.p[c] = pack16g(p[2*c], p[2*c+1]);
            wa[mt][ks] = u.v;
        }
        #pragma unroll
        for (int ks = 0; ks < 2; ++ks) {
            const float* p = W_ih + (size_t)row * D_IN + ks * 32 + colg * 8;
            FR u;
            #pragma unroll
            for (int c = 0; c < 4; ++c) u.p[c] = pack16g(p[2*c], p[2*c+1]);
            xa[mt][ks] = u.v;
        }
        #pragma unroll
        for (int reg = 0; reg < 4; ++reg) {
            const int r2 = rowbase + mt * 16 + colg * 4 + reg;  // C row map
            bias[mt * 4 + reg] = b_ih[r2] + b_hh[r2];
        }
    }
    float c_reg = (tid < H_DIM) ? c0[b * H_DIM + tid] : 0.f;

    // ---- one-time: done mask, h0 (pre-scaled), x ring prologue ----
    smask[tid] = 1.0f - done[(size_t)tid * B_ENV + b];   // tid == t
    if (tid < 64) {
        const float sm0 = 1.0f - done[b];
        const float* hp = h0 + b * H_DIM;
        ((g2*)&h16[0][0])[tid] = pack16g(hp[2*tid] * sm0, hp[2*tid+1] * sm0);
    }
    if (wid == 0) {
        #pragma unroll
        for (int s = 0; s < 3; ++s)
            async_load_row(x + ((size_t)s * B_ENV + b) * D_IN + lane, &xring[s][0]);
    }
    __syncthreads();                 // full drain once: x0..x2 landed
    if (wid == 0 && lane < 32) {     // convert x0 -> x16[0]
        float2 v = *reinterpret_cast<const float2*>(&xring[0][2 * lane]);
        ((g2*)&x16[0][0])[lane] = pack16g(v.x, v.y);
    }
    sync_lds();

    for (int t = 0; t < T_STEPS; ++t) {
        const int rb = t & 1, wb = rb ^ 1;

        if (wid == 0) {
            const int t3 = (t + 3 < T_STEPS) ? (t + 3) : (T_STEPS - 1);
            async_load_row(x + ((size_t)t3 * B_ENV + b) * D_IN + lane,
                           &xring[(t + 3) & 3][0]);
            if (lane < 32) {   // convert x_{t+1} (landed: last step's vmcnt)
                float2 v = *reinterpret_cast<const float2*>(
                    &xring[(t + 1) & 3][2 * lane]);
                ((g2*)&x16[wb][0])[lane] = pack16g(v.x, v.y);
            }
        }

        // ---- B-fragments: k-contiguous per lane group, cols replicated ----
        const g8* hbp = reinterpret_cast<const g8*>(&h16[rb][0]);
        const g8  hB0 = hbp[colg], hB1 = hbp[4 + colg],
                  hB2 = hbp[8 + colg], hB3 = hbp[12 + colg];
        const g8* xbp = reinterpret_cast<const g8*>(&x16[rb][0]);
        const g8  xB0 = xbp[colg], xB1 = xbp[4 + colg];

        // ---- 4 M-tiles x (4 + 2) MFMA, bias as acc-init ----
        #pragma unroll
        for (int mt = 0; mt < 4; ++mt) {
            f4v acc = { bias[mt*4+0], bias[mt*4+1], bias[mt*4+2], bias[mt*4+3] };
            acc = mfma16(wa[mt][0], hB0, acc);
            acc = mfma16(wa[mt][1], hB1, acc);
            acc = mfma16(wa[mt][2], hB2, acc);
            acc = mfma16(wa[mt][3], hB3, acc);
            acc = mfma16(xa[mt][0], xB0, acc);
            acc = mfma16(xa[mt][1], xB1, acc);
            // activation (wave-uniform gate type)
            f4v av;
            #pragma unroll
            for (int reg = 0; reg < 4; ++reg) {
                const float v = acc[reg];
                av[reg] = (g == 2) ? tanh_f(v) : sigm(v);
            }
            if (rml == 0)   // col-0 lanes hold rows colg*4..+3 of this tile
                *reinterpret_cast<f4v*>(&g_lds[g][jb + mt * 16 + colg * 4]) = av;
        }
        sync_lds();   // barrier 1: g_lds ready

        if (wid == 0) {
            // counted wait: queue = [L(t+2), S(t-1), L(t+3)] -> retire L(t+2)
            // only (next step's conversion); never blocks on the hs store.
            asm volatile("s_waitcnt vmcnt(2)" ::: "memory");
        }
        if (tid < H_DIM) {
            const float dm = smask[t];
            const float gi = g_lds[0][tid];
            const float gf = g_lds[1][tid];
            const float gg = g_lds[2][tid];
            const float go = g_lds[3][tid];
            const float cn = gf * (c_reg * dm) + gi * gg;
            c_reg = cn;
            const float hn = go * tanh_f(cn);
            const float smn = smask[(t + 1 < T_STEPS) ? (t + 1) : (T_STEPS - 1)];
            h16[wb][tid] = (__fp16)(hn * smn);
            hs[((size_t)t * B_ENV + b) * H_DIM + tid] = hn;   // stays in flight
        }
        sync_lds();   // barrier 2: h_t, x16_{t+1}, x_{t+2} all published
    }
}

// In-place row projection: out[r,:] = out_row @ W_hid^T + b_hid.
// 1024 blocks x 256 threads; block owns 128 rows (disjoint -> in-place safe).
#define PADK 68
__global__ __launch_bounds__(256)
void ppo_proj(const float* __restrict__ W_hid,   // [H,H]
              const float* __restrict__ b_hid,   // [H]
              float* __restrict__ out)           // [T*B, H] in-place
{
    __shared__ h2v wl[H_DIM][PADK];
    __shared__ h2v hl[H_DIM][PADK];
    const int tid = threadIdx.x;
    const int rg  = tid >> 4;
    const int cg  = tid & 15;

    const size_t r0 = (size_t)blockIdx.x * H_DIM;

    #pragma unroll
    for (int i = 0; i < 16; ++i) {
        const int idx = tid + 256 * i;
        const int r = idx >> 5, cc = idx & 31;
        f4v v = *reinterpret_cast<const f4v*>(W_hid + 4 * (size_t)idx);
        wl[r][2 * cc]     = pack16(v.x, v.y);
        wl[r][2 * cc + 1] = pack16(v.z, v.w);
    }
    #pragma unroll
    for (int i = 0; i < 16; ++i) {
        const int idx = tid + 256 * i;
        const int r = idx >> 5, cc = idx & 31;
        f4v v = *reinterpret_cast<const f4v*>(out + (r0 + r) * H_DIM + 4 * cc);
        hl[r][2 * cc]     = pack16(v.x, v.y);
        hl[r][2 * cc + 1] = pack16(v.z, v.w);
    }
    float bcol[8];
    #pragma unroll
    for (int jj = 0; jj < 8; ++jj) bcol[jj] = b_hid[cg + 16 * jj];
    __syncthreads();

    float acc[8][8];
    #pragma unroll
    for (int i = 0; i < 8; ++i)
        #pragma unroll
        for (int jj = 0; jj < 8; ++jj) acc[i][jj] = 0.f;

    for (int kq = 0; kq < 16; ++kq) {
        union { h8v v; h2v p[4]; } hv[8], wv[8];
        #pragma unroll
        for (int i = 0; i < 8; ++i)
            hv[i].v = *reinterpret_cast<const h8v*>(&hl[rg * 8 + i][4 * kq]);
        #pragma unroll
        for (int jj = 0; jj < 8; ++jj)
            wv[jj].v = *reinterpret_cast<const h8v*>(&wl[cg + 16 * jj][4 * kq]);
        #pragma unroll
        for (int i = 0; i < 8; ++i)
            #pragma unroll
            for (int jj = 0; jj < 8; ++jj) {
                acc[i][jj] = dot2(hv[i].p[0], wv[jj].p[0], acc[i][jj]);
                acc[i][jj] = dot2(hv[i].p[1], wv[jj].p[1], acc[i][jj]);
                acc[i][jj] = dot2(hv[i].p[2], wv[jj].p[2], acc[i][jj]);
                acc[i][jj] = dot2(hv[i].p[3], wv[jj].p[3], acc[i][jj]);
            }
    }

    #pragma unroll
    for (int i = 0; i < 8; ++i)
        #pragma unroll
        for (int jj = 0; jj < 8; ++jj)
            out[(r0 + rg * 8 + i) * H_DIM + cg + 16 * jj] = acc[i][jj] + bcol[jj];
}

extern "C" void kernel_launch(void* const* d_in, const int* in_sizes, int n_in,
                              void* d_out, int out_size, void* d_ws, size_t ws_size,
                              hipStream_t stream) {
    const float* x     = (const float*)d_in[0];
    const float* done  = (const float*)d_in[1];
    const float* h0    = (const float*)d_in[2];
    const float* c0    = (const float*)d_in[3];
    const float* W_ih  = (const float*)d_in[4];
    const float* b_ih  = (const float*)d_in[5];
    const float* W_hh  = (const float*)d_in[6];
    const float* b_hh  = (const float*)d_in[7];
    const float* W_hid = (const float*)d_in[8];
    const float* b_hid = (const float*)d_in[9];
    float* out = (float*)d_out;
    (void)d_ws; (void)ws_size; (void)out_size; (void)n_in; (void)in_sizes;

    hipLaunchKernelGGL(ppo_lstm_scan, dim3(B_ENV), dim3(512), 0, stream,
                       x, done, h0, c0, W_ih, b_ih, W_hh, b_hh, out);
    hipLaunchKernelGGL(ppo_proj, dim3((T_STEPS * B_ENV) / H_DIM), dim3(256), 0, stream,
                       W_hid, b_hid, out);
}

// Round 14
// 462.485 us; speedup vs baseline: 1.7607x; 1.7607x over previous
//
#include <hip/hip_runtime.h>

#define T_STEPS 512
#define B_ENV   256
#define D_IN    64
#define H_DIM   128
#define G4      512   // 4*H gate rows

typedef _Float16 h2v __attribute__((ext_vector_type(2)));
typedef _Float16 h8v __attribute__((ext_vector_type(8)));
typedef float    f4v __attribute__((ext_vector_type(4)));

__device__ __forceinline__ float dot2(h2v a, h2v b, float c) {
#if __has_builtin(__builtin_amdgcn_fdot2)
    return __builtin_amdgcn_fdot2(a, b, c, false);
#else
    return c + (float)a.x * (float)b.x + (float)a.y * (float)b.y;
#endif
}

__device__ __forceinline__ h2v pack16(float a, float b) {
#if __has_builtin(__builtin_amdgcn_cvt_pkrtz)
    union { __fp16 __attribute__((ext_vector_type(2))) r; h2v h; } u;
    u.r = __builtin_amdgcn_cvt_pkrtz(a, b);
    return u.h;
#else
    h2v p; p.x = (_Float16)a; p.y = (_Float16)b; return p;
#endif
}

__device__ __forceinline__ float fast_rcp(float x) {
#if __has_builtin(__builtin_amdgcn_rcpf)
    return __builtin_amdgcn_rcpf(x);
#else
    return 1.0f / x;
#endif
}
__device__ __forceinline__ float sigm(float x)   { return fast_rcp(1.0f + __expf(-x)); }
__device__ __forceinline__ float tanh_f(float x) { float e = __expf(2.0f * x); return 1.0f - 2.0f * fast_rcp(e + 1.0f); }

// DPP quad_perm ops (VALU pipe — never LDS).
template <int CTRL>
__device__ __forceinline__ float dpp_mov(float v) {
    int s = __builtin_amdgcn_update_dpp(
        0, __builtin_bit_cast(int, v), CTRL, 0xF, 0xF, true);
    return __builtin_bit_cast(float, s);
}
__device__ __forceinline__ float quad_allreduce(float v) {
    v += dpp_mov<0xB1>(v);   // quad_perm(1,0,3,2): xor1
    v += dpp_mov<0x4E>(v);   // quad_perm(2,3,0,1): xor2
    return v;
}

// Barrier draining LDS ops only — global loads/stores stay in flight.
__device__ __forceinline__ void sync_lds() {
    asm volatile("s_waitcnt lgkmcnt(0)" ::: "memory");
    __builtin_amdgcn_s_barrier();
    asm volatile("" ::: "memory");
}

// Scan: one block per env, 512 threads = 8 IDENTICAL waves, ONE lgkm
// barrier per step, ZERO explicit vmcnt waits.
// R9 post-mortem: wave 0's `vmcnt(1)` sat behind its own hs store in the
// FIFO -> it retired the store (HBM ack) every step and delayed the
// barrier for all waves. Fix: no ring, no special wave. Each thread
// prefetches its own x-quarter (16 floats, 4x dwordx4, L1/L2-resident)
// one step ahead into registers: convert at top of step (frees regs),
// re-issue loads for t+1 right after -> queue [L x4, S], compiler waits
// never block on the store, latency budget = one full step.
// Thread (j=tid>>2, qq=tid&3) owns k-quarter qq of gate rows
// {j,128+j,256+j,384+j} (W_hh 64 h2v + W_ih 32 h2v in registers).
// Per step: 4 ds_read_b128 (h quarter) -> 96 dot2 -> DPP quad allreduce
// -> lane qq activates gate qq -> DPP broadcast -> replicated cell
// update -> qq==0 writes h16 (pre-scaled by smask[t+1]) + raw h to hs.
__global__ __launch_bounds__(512, 1) __attribute__((amdgpu_waves_per_eu(2, 2)))
void ppo_lstm_scan(const float* __restrict__ x,      // [T,B,D]
                   const float* __restrict__ done,   // [T,B]
                   const float* __restrict__ h0,     // [B,H]
                   const float* __restrict__ c0,     // [B,H]
                   const float* __restrict__ W_ih,   // [4H,D]
                   const float* __restrict__ b_ih,   // [4H]
                   const float* __restrict__ W_hh,   // [4H,H]
                   const float* __restrict__ b_hh,   // [4H]
                   float* __restrict__ hs)           // [T,B,H] = d_out (raw h)
{
    const int b   = blockIdx.x;
    const int tid = threadIdx.x;
    const int qq  = tid & 3;
    const int j   = tid >> 2;

    __shared__ alignas(16) h2v   h16[2][H_DIM / 2];  // h f16 (pre-masked), dbuf
    __shared__ alignas(16) float smask[T_STEPS];     // 1-done

    // ---- one-time: weight slices -> registers (f16) ----
    h2v whh[64];   // gate g, k-quarter qq: 16 h2v each
    h2v wih[32];   // gate g, x-quarter qq: 8 h2v each
    #pragma unroll
    for (int g = 0; g < 4; ++g) {
        const float* wr = W_hh + (size_t)(g * H_DIM + j) * H_DIM + qq * 32;
        #pragma unroll
        for (int c = 0; c < 16; ++c)
            whh[g * 16 + c] = pack16(wr[2 * c], wr[2 * c + 1]);
        const float* wr2 = W_ih + (size_t)(g * H_DIM + j) * D_IN + qq * 16;
        #pragma unroll
        for (int c = 0; c < 8; ++c)
            wih[g * 8 + c] = pack16(wr2[2 * c], wr2[2 * c + 1]);
    }
    const int   r_own    = qq * H_DIM + j;
    const float bias_own = b_ih[r_own] + b_hh[r_own];
    float       c_reg    = c0[b * H_DIM + j];

    // ---- one-time: done mask, h0 (pre-scaled), x0 prefetch ----
    smask[tid] = 1.0f - done[(size_t)tid * B_ENV + b];   // tid == t
    if (tid < 64) {
        const float sm0 = 1.0f - done[b];
        const float* hp = h0 + b * H_DIM;
        h16[0][tid] = pack16(hp[2 * tid] * sm0, hp[2 * tid + 1] * sm0);
    }
    f4v xr[4];   // per-thread x-quarter prefetch (t=0)
    {
        const float* xp = x + (size_t)b * D_IN + qq * 16;
        #pragma unroll
        for (int i = 0; i < 4; ++i)
            xr[i] = *reinterpret_cast<const f4v*>(xp + 4 * i);
    }
    __syncthreads();

    for (int t = 0; t < T_STEPS; ++t) {
        const int rb = t & 1, wb = rb ^ 1;

        // ---- convert this step's x quarter (waits on loads, not stores) ----
        h2v xh[8];
        #pragma unroll
        for (int i = 0; i < 4; ++i) {
            xh[2 * i]     = pack16(xr[i].x, xr[i].y);
            xh[2 * i + 1] = pack16(xr[i].z, xr[i].w);
        }
        // ---- immediately issue x prefetch for t+1 (full-step latency) ----
        {
            const int tn = (t + 1 < T_STEPS) ? (t + 1) : t;
            const float* xp = x + ((size_t)tn * B_ENV + b) * D_IN + qq * 16;
            #pragma unroll
            for (int i = 0; i < 4; ++i)
                xr[i] = *reinterpret_cast<const f4v*>(xp + 4 * i);
        }

        // ---- k-quarter dots: 4 ds_read_b128 (h) + register x ----
        const h8v* hp8 = reinterpret_cast<const h8v*>(&h16[rb][qq * 16]);
        float s0 = 0.f, s1 = 0.f, s2 = 0.f, s3 = 0.f;
        #pragma unroll
        for (int c4 = 0; c4 < 4; ++c4) {
            union { h8v v; h2v p[4]; } u;
            u.v = hp8[c4];
            #pragma unroll
            for (int pp = 0; pp < 4; ++pp) {
                s0 = dot2(whh[      c4 * 4 + pp], u.p[pp], s0);
                s1 = dot2(whh[16 +  c4 * 4 + pp], u.p[pp], s1);
                s2 = dot2(whh[32 +  c4 * 4 + pp], u.p[pp], s2);
                s3 = dot2(whh[48 +  c4 * 4 + pp], u.p[pp], s3);
            }
        }
        #pragma unroll
        for (int c = 0; c < 8; ++c) {
            s0 = dot2(wih[     c], xh[c], s0);
            s1 = dot2(wih[ 8 + c], xh[c], s1);
            s2 = dot2(wih[16 + c], xh[c], s2);
            s3 = dot2(wih[24 + c], xh[c], s3);
        }

        // ---- quad allreduce (h pre-masked -> no dm in dot path) ----
        s0 = quad_allreduce(s0);
        s1 = quad_allreduce(s1);
        s2 = quad_allreduce(s2);
        s3 = quad_allreduce(s3);

        // ---- lane qq activates its own gate, then quad-broadcast ----
        const float s01 = (qq & 1) ? s1 : s0;
        const float s23 = (qq & 1) ? s3 : s2;
        const float gs  = ((qq & 2) ? s23 : s01) + bias_own;
        const float av  = (qq == 2) ? tanh_f(gs) : sigm(gs);
        const float ai  = dpp_mov<0x00>(av);
        const float af  = dpp_mov<0x55>(av);
        const float ag  = dpp_mov<0xAA>(av);
        const float ao  = dpp_mov<0xFF>(av);

        // ---- cell update, replicated (bit-identical) in quad ----
        const float dm = smask[t];
        const float cn = af * (c_reg * dm) + ai * ag;
        c_reg = cn;
        const float hn = ao * tanh_f(cn);

        if (qq == 0) {
            const float smn = smask[(t + 1 < T_STEPS) ? (t + 1) : (T_STEPS - 1)];
            reinterpret_cast<_Float16*>(h16[wb])[j] = (_Float16)(hn * smn);
            hs[((size_t)t * B_ENV + b) * H_DIM + j] = hn;   // fire-and-forget
        }
        sync_lds();   // single barrier: h_t published
    }
}

// In-place row projection: out[r,:] = out_row @ W_hid^T + b_hid.
// 1024 blocks x 256 threads; block owns 128 rows (disjoint -> in-place safe).
#define PADK 68
__global__ __launch_bounds__(256)
void ppo_proj(const float* __restrict__ W_hid,   // [H,H]
              const float* __restrict__ b_hid,   // [H]
              float* __restrict__ out)           // [T*B, H] in-place
{
    __shared__ h2v wl[H_DIM][PADK];
    __shared__ h2v hl[H_DIM][PADK];
    const int tid = threadIdx.x;
    const int rg  = tid >> 4;
    const int cg  = tid & 15;

    const size_t r0 = (size_t)blockIdx.x * H_DIM;

    #pragma unroll
    for (int i = 0; i < 16; ++i) {
        const int idx = tid + 256 * i;
        const int r = idx >> 5, cc = idx & 31;
        f4v v = *reinterpret_cast<const f4v*>(W_hid + 4 * (size_t)idx);
        wl[r][2 * cc]     = pack16(v.x, v.y);
        wl[r][2 * cc + 1] = pack16(v.z, v.w);
    }
    #pragma unroll
    for (int i = 0; i < 16; ++i) {
        const int idx = tid + 256 * i;
        const int r = idx >> 5, cc = idx & 31;
        f4v v = *reinterpret_cast<const f4v*>(out + (r0 + r) * H_DIM + 4 * cc);
        hl[r][2 * cc]     = pack16(v.x, v.y);
        hl[r][2 * cc + 1] = pack16(v.z, v.w);
    }
    float bcol[8];
    #pragma unroll
    for (int jj = 0; jj < 8; ++jj) bcol[jj] = b_hid[cg + 16 * jj];
    __syncthreads();

    float acc[8][8];
    #pragma unroll
    for (int i = 0; i < 8; ++i)
        #pragma unroll
        for (int jj = 0; jj < 8; ++jj) acc[i][jj] = 0.f;

    for (int kq = 0; kq < 16; ++kq) {
        union { h8v v; h2v p[4]; } hv[8], wv[8];
        #pragma unroll
        for (int i = 0; i < 8; ++i)
            hv[i].v = *reinterpret_cast<const h8v*>(&hl[rg * 8 + i][4 * kq]);
        #pragma unroll
        for (int jj = 0; jj < 8; ++jj)
            wv[jj].v = *reinterpret_cast<const h8v*>(&wl[cg + 16 * jj][4 * kq]);
        #pragma unroll
        for (int i = 0; i < 8; ++i)
            #pragma unroll
            for (int jj = 0; jj < 8; ++jj) {
                acc[i][jj] = dot2(hv[i].p[0], wv[jj].p[0], acc[i][jj]);
                acc[i][jj] = dot2(hv[i].p[1], wv[jj].p[1], acc[i][jj]);
                acc[i][jj] = dot2(hv[i].p[2], wv[jj].p[2], acc[i][jj]);
                acc[i][jj] = dot2(hv[i].p[3], wv[jj].p[3], acc[i][jj]);
            }
    }

    #pragma unroll
    for (int i = 0; i < 8; ++i)
        #pragma unroll
        for (int jj = 0; jj < 8; ++jj)
            out[(r0 + rg * 8 + i) * H_DIM + cg + 16 * jj] = acc[i][jj] + bcol[jj];
}

extern "C" void kernel_launch(void* const* d_in, const int* in_sizes, int n_in,
                              void* d_out, int out_size, void* d_ws, size_t ws_size,
                              hipStream_t stream) {
    const float* x     = (const float*)d_in[0];
    const float* done  = (const float*)d_in[1];
    const float* h0    = (const float*)d_in[2];
    const float* c0    = (const float*)d_in[3];
    const float* W_ih  = (const float*)d_in[4];
    const float* b_ih  = (const float*)d_in[5];
    const float* W_hh  = (const float*)d_in[6];
    const float* b_hh  = (const float*)d_in[7];
    const float* W_hid = (const float*)d_in[8];
    const float* b_hid = (const float*)d_in[9];
    float* out = (float*)d_out;
    (void)d_ws; (void)ws_size; (void)out_size; (void)n_in; (void)in_sizes;

    hipLaunchKernelGGL(ppo_lstm_scan, dim3(B_ENV), dim3(512), 0, stream,
                       x, done, h0, c0, W_ih, b_ih, W_hh, b_hh, out);
    hipLaunchKernelGGL(ppo_proj, dim3((T_STEPS * B_ENV) / H_DIM), dim3(256), 0, stream,
                       W_hid, b_hid, out);
}

// Round 15
// 367.746 us; speedup vs baseline: 2.2142x; 1.2576x over previous
//
#include <hip/hip_runtime.h>

#define T_STEPS 512
#define B_ENV   256
#define D_IN    64
#define H_DIM   128
#define G4      512   // 4*H gate rows

typedef _Float16 h2v __attribute__((ext_vector_type(2)));
typedef _Float16 h8v __attribute__((ext_vector_type(8)));
typedef float    f4v __attribute__((ext_vector_type(4)));
typedef __fp16   g2  __attribute__((ext_vector_type(2)));
typedef __fp16   g8  __attribute__((ext_vector_type(8)));

__device__ __forceinline__ float dot2(h2v a, h2v b, float c) {
#if __has_builtin(__builtin_amdgcn_fdot2)
    return __builtin_amdgcn_fdot2(a, b, c, false);
#else
    return c + (float)a.x * (float)b.x + (float)a.y * (float)b.y;
#endif
}

__device__ __forceinline__ g2 pack16g(float a, float b) {
#if __has_builtin(__builtin_amdgcn_cvt_pkrtz)
    return __builtin_amdgcn_cvt_pkrtz(a, b);
#else
    g2 p; p.x = (__fp16)a; p.y = (__fp16)b; return p;
#endif
}
__device__ __forceinline__ h2v pack16(float a, float b) {
    union { g2 r; h2v h; } u; u.r = pack16g(a, b); return u.h;
}

__device__ __forceinline__ f4v mfma16(g8 a, g8 b, f4v c) {
    return __builtin_amdgcn_mfma_f32_16x16x32_f16(a, b, c, 0, 0, 0);
}

__device__ __forceinline__ float fast_rcp(float x) {
#if __has_builtin(__builtin_amdgcn_rcpf)
    return __builtin_amdgcn_rcpf(x);
#else
    return 1.0f / x;
#endif
}
__device__ __forceinline__ float sigm(float x)   { return fast_rcp(1.0f + __expf(-x)); }
__device__ __forceinline__ float tanh_f(float x) { float e = __expf(2.0f * x); return 1.0f - 2.0f * fast_rcp(e + 1.0f); }

// DPP quad_perm ops (VALU pipe — never LDS).
template <int CTRL>
__device__ __forceinline__ float dpp_mov(float v) {
    int s = __builtin_amdgcn_update_dpp(
        0, __builtin_bit_cast(int, v), CTRL, 0xF, 0xF, true);
    return __builtin_bit_cast(float, s);
}
__device__ __forceinline__ float quad_allreduce(float v) {
    v += dpp_mov<0xB1>(v);   // quad_perm(1,0,3,2): xor1
    v += dpp_mov<0x4E>(v);   // quad_perm(2,3,0,1): xor2
    return v;
}

// Barrier draining LDS ops only — global loads/stores stay in flight.
__device__ __forceinline__ void sync_lds() {
    asm volatile("s_waitcnt lgkmcnt(0)" ::: "memory");
    __builtin_amdgcn_s_barrier();
    asm volatile("" ::: "memory");
}

// ---------------------------------------------------------------------------
// xg GEMM: xg[tb, r] = x[tb,:] . W_ih[r,:]  (f16 out, NO bias — scan adds it)
// M = T*B = 131072 (2048 blocks x 64 rows), N = 512, K = 64. MFMA 16x16x32.
// W_ih staged once per block in LDS (512 x 64 f16, rows padded to 72 f16 =
// 144B: bank(col) = 4*col mod 32 -> 2-way alias = free). A-frags from global
// (f32 -> f16 pack). Fragment maps per m89 (same as R13, which passed):
//   A: row = lane&15, kgroup = lane>>4 ; B: col = lane&15, kgroup = lane>>4 ;
//   C: col = lane&15, row = (lane>>4)*4 + reg.
__global__ __launch_bounds__(256)
void ppo_xg(const float* __restrict__ x,     // [T*B, 64]
            const float* __restrict__ W_ih,  // [512, 64]
            unsigned short* __restrict__ xg) // [T*B, 512] f16 bits
{
    const int tid  = threadIdx.x;
    const int lane = tid & 63;
    const int w    = tid >> 6;
    const int rml  = lane & 15;
    const int colg = lane >> 4;

    __shared__ h2v wl[G4][36];   // 512 rows x 32 h2v (+4 pad) = 72 KB

    #pragma unroll
    for (int i = 0; i < 32; ++i) {             // stage W_ih: 8192 f4v
        const int idx = tid + 256 * i;
        const int r = idx >> 4, cc = idx & 15;
        f4v v = *reinterpret_cast<const f4v*>(W_ih + (size_t)idx * 4);
        wl[r][2 * cc]     = pack16(v.x, v.y);
        wl[r][2 * cc + 1] = pack16(v.z, v.w);
    }
    __syncthreads();

    const size_t row0 = (size_t)blockIdx.x * 64 + w * 16;

    // A-frags: 2 K-strips of x rows (lane rml = row, colg = k-group)
    g8 a[2];
    #pragma unroll
    for (int ks = 0; ks < 2; ++ks) {
        const float* p = x + (row0 + rml) * D_IN + ks * 32 + colg * 8;
        union { g2 q[4]; g8 v; } u;
        #pragma unroll
        for (int c = 0; c < 4; ++c) u.q[c] = pack16g(p[2 * c], p[2 * c + 1]);
        a[ks] = u.v;
    }

    #pragma unroll 4
    for (int ct = 0; ct < 32; ++ct) {          // 32 column tiles of 16 gates
        const int col = ct * 16 + rml;         // B col = lane&15
        const g8 b0 = *reinterpret_cast<const g8*>(&wl[col][colg * 4]);
        const g8 b1 = *reinterpret_cast<const g8*>(&wl[col][16 + colg * 4]);
        f4v acc = {0.f, 0.f, 0.f, 0.f};
        acc = mfma16(a[0], b0, acc);
        acc = mfma16(a[1], b1, acc);
        // C: row = colg*4+reg, col = rml
        #pragma unroll
        for (int reg = 0; reg < 4; ++reg) {
            const __fp16 hv = (__fp16)acc[reg];
            xg[(row0 + colg * 4 + reg) * G4 + ct * 16 + rml] =
                __builtin_bit_cast(unsigned short, hv);
        }
    }
}

// ---------------------------------------------------------------------------
// Scan with precomputed xg: one block per env, 512 threads = 8 waves, ONE
// lgkm barrier/step. Thread (j=tid>>2, qq=tid&3) owns k-quarter qq of gate
// rows {j,128+j,256+j,384+j} of W_hh only (64 h2v). Per step:
// 4 ds_read_b128 (h) -> 64 dot2 -> DPP quad allreduce -> lane qq adds its
// own xg (ONE u16 scalar, prefetched a full step ahead) + bias, activates,
// DPP-broadcasts -> replicated cell update -> qq==0 writes h16 (pre-scaled
// by smask[t+1]) + raw h to hs. dm carried in a register across steps.
__global__ __launch_bounds__(512, 1) __attribute__((amdgpu_waves_per_eu(2, 2)))
void ppo_lstm_scan_xg(const unsigned short* __restrict__ xg,  // [T,B,4H] f16
                      const float* __restrict__ done,   // [T,B]
                      const float* __restrict__ h0,     // [B,H]
                      const float* __restrict__ c0,     // [B,H]
                      const float* __restrict__ b_ih,   // [4H]
                      const float* __restrict__ W_hh,   // [4H,H]
                      const float* __restrict__ b_hh,   // [4H]
                      float* __restrict__ hs)           // [T,B,H] = d_out
{
    const int b   = blockIdx.x;
    const int tid = threadIdx.x;
    const int qq  = tid & 3;
    const int j   = tid >> 2;

    __shared__ alignas(16) h2v   h16[2][H_DIM / 2];  // h f16 (pre-masked), dbuf
    __shared__ alignas(16) float smask[T_STEPS];     // 1-done

    h2v whh[64];   // gate g, k-quarter qq: 16 h2v each
    #pragma unroll
    for (int g = 0; g < 4; ++g) {
        const float* wr = W_hh + (size_t)(g * H_DIM + j) * H_DIM + qq * 32;
        #pragma unroll
        for (int c = 0; c < 16; ++c)
            whh[g * 16 + c] = pack16(wr[2 * c], wr[2 * c + 1]);
    }
    const int   r_own    = qq * H_DIM + j;
    const float bias_own = b_ih[r_own] + b_hh[r_own];
    float       c_reg    = c0[b * H_DIM + j];

    smask[tid] = 1.0f - done[(size_t)tid * B_ENV + b];   // tid == t
    if (tid < 64) {
        const float sm0 = 1.0f - done[b];
        const float* hp = h0 + b * H_DIM;
        h16[0][tid] = pack16(hp[2 * tid] * sm0, hp[2 * tid + 1] * sm0);
    }
    // xg prefetch for t=0
    const unsigned short* xgp = xg + (size_t)b * G4 + r_own;
    unsigned short xcur = xgp[0];
    __syncthreads();

    float dm = 1.0f - done[b];   // == smask[0]

    for (int t = 0; t < T_STEPS; ++t) {
        const int rb = t & 1, wb = rb ^ 1;

        // prefetch next step's xg (full-step latency budget)
        const int tn = (t + 1 < T_STEPS) ? (t + 1) : t;
        const unsigned short xnext = xgp[(size_t)tn * B_ENV * G4];

        // ---- k-quarter dots vs h (h pre-masked) ----
        const h8v* hp8 = reinterpret_cast<const h8v*>(&h16[rb][qq * 16]);
        float s0 = 0.f, s1 = 0.f, s2 = 0.f, s3 = 0.f;
        #pragma unroll
        for (int c4 = 0; c4 < 4; ++c4) {
            union { h8v v; h2v p[4]; } u;
            u.v = hp8[c4];
            #pragma unroll
            for (int pp = 0; pp < 4; ++pp) {
                s0 = dot2(whh[      c4 * 4 + pp], u.p[pp], s0);
                s1 = dot2(whh[16 +  c4 * 4 + pp], u.p[pp], s1);
                s2 = dot2(whh[32 +  c4 * 4 + pp], u.p[pp], s2);
                s3 = dot2(whh[48 +  c4 * 4 + pp], u.p[pp], s3);
            }
        }

        s0 = quad_allreduce(s0);
        s1 = quad_allreduce(s1);
        s2 = quad_allreduce(s2);
        s3 = quad_allreduce(s3);

        // ---- lane qq: own gate = sum + xg + bias, activate, broadcast ----
        const float xgf = (float)__builtin_bit_cast(__fp16, xcur);
        const float s01 = (qq & 1) ? s1 : s0;
        const float s23 = (qq & 1) ? s3 : s2;
        const float gs  = ((qq & 2) ? s23 : s01) + bias_own + xgf;
        const float av  = (qq == 2) ? tanh_f(gs) : sigm(gs);
        const float ai  = dpp_mov<0x00>(av);
        const float af  = dpp_mov<0x55>(av);
        const float ag  = dpp_mov<0xAA>(av);
        const float ao  = dpp_mov<0xFF>(av);

        // ---- cell update, replicated (bit-identical) in quad ----
        const float cn = af * (c_reg * dm) + ai * ag;
        c_reg = cn;
        const float hn = ao * tanh_f(cn);

        const float smn = smask[(t + 1 < T_STEPS) ? (t + 1) : (T_STEPS - 1)];
        if (qq == 0) {
            reinterpret_cast<_Float16*>(h16[wb])[j] = (_Float16)(hn * smn);
            hs[((size_t)t * B_ENV + b) * H_DIM + j] = hn;   // fire-and-forget
        }
        dm   = smn;     // next step's mask, no extra LDS read
        xcur = xnext;
        sync_lds();     // single barrier: h_t published
    }
}

// ---------------------------------------------------------------------------
// Fallback scan (R14 verbatim): used when ws_size can't hold xg.
__global__ __launch_bounds__(512, 1) __attribute__((amdgpu_waves_per_eu(2, 2)))
void ppo_lstm_scan_fb(const float* __restrict__ x,
                      const float* __restrict__ done,
                      const float* __restrict__ h0,
                      const float* __restrict__ c0,
                      const float* __restrict__ W_ih,
                      const float* __restrict__ b_ih,
                      const float* __restrict__ W_hh,
                      const float* __restrict__ b_hh,
                      float* __restrict__ hs)
{
    const int b   = blockIdx.x;
    const int tid = threadIdx.x;
    const int qq  = tid & 3;
    const int j   = tid >> 2;

    __shared__ alignas(16) h2v   h16[2][H_DIM / 2];
    __shared__ alignas(16) float smask[T_STEPS];

    h2v whh[64];
    h2v wih[32];
    #pragma unroll
    for (int g = 0; g < 4; ++g) {
        const float* wr = W_hh + (size_t)(g * H_DIM + j) * H_DIM + qq * 32;
        #pragma unroll
        for (int c = 0; c < 16; ++c)
            whh[g * 16 + c] = pack16(wr[2 * c], wr[2 * c + 1]);
        const float* wr2 = W_ih + (size_t)(g * H_DIM + j) * D_IN + qq * 16;
        #pragma unroll
        for (int c = 0; c < 8; ++c)
            wih[g * 8 + c] = pack16(wr2[2 * c], wr2[2 * c + 1]);
    }
    const int   r_own    = qq * H_DIM + j;
    const float bias_own = b_ih[r_own] + b_hh[r_own];
    float       c_reg    = c0[b * H_DIM + j];

    smask[tid] = 1.0f - done[(size_t)tid * B_ENV + b];
    if (tid < 64) {
        const float sm0 = 1.0f - done[b];
        const float* hp = h0 + b * H_DIM;
        h16[0][tid] = pack16(hp[2 * tid] * sm0, hp[2 * tid + 1] * sm0);
    }
    f4v xr[4];
    {
        const float* xp = x + (size_t)b * D_IN + qq * 16;
        #pragma unroll
        for (int i = 0; i < 4; ++i)
            xr[i] = *reinterpret_cast<const f4v*>(xp + 4 * i);
    }
    __syncthreads();

    for (int t = 0; t < T_STEPS; ++t) {
        const int rb = t & 1, wb = rb ^ 1;

        h2v xh[8];
        #pragma unroll
        for (int i = 0; i < 4; ++i) {
            xh[2 * i]     = pack16(xr[i].x, xr[i].y);
            xh[2 * i + 1] = pack16(xr[i].z, xr[i].w);
        }
        {
            const int tn = (t + 1 < T_STEPS) ? (t + 1) : t;
            const float* xp = x + ((size_t)tn * B_ENV + b) * D_IN + qq * 16;
            #pragma unroll
            for (int i = 0; i < 4; ++i)
                xr[i] = *reinterpret_cast<const f4v*>(xp + 4 * i);
        }

        const h8v* hp8 = reinterpret_cast<const h8v*>(&h16[rb][qq * 16]);
        float s0 = 0.f, s1 = 0.f, s2 = 0.f, s3 = 0.f;
        #pragma unroll
        for (int c4 = 0; c4 < 4; ++c4) {
            union { h8v v; h2v p[4]; } u;
            u.v = hp8[c4];
            #pragma unroll
            for (int pp = 0; pp < 4; ++pp) {
                s0 = dot2(whh[      c4 * 4 + pp], u.p[pp], s0);
                s1 = dot2(whh[16 +  c4 * 4 + pp], u.p[pp], s1);
                s2 = dot2(whh[32 +  c4 * 4 + pp], u.p[pp], s2);
                s3 = dot2(whh[48 +  c4 * 4 + pp], u.p[pp], s3);
            }
        }
        #pragma unroll
        for (int c = 0; c < 8; ++c) {
            s0 = dot2(wih[     c], xh[c], s0);
            s1 = dot2(wih[ 8 + c], xh[c], s1);
            s2 = dot2(wih[16 + c], xh[c], s2);
            s3 = dot2(wih[24 + c], xh[c], s3);
        }

        s0 = quad_allreduce(s0);
        s1 = quad_allreduce(s1);
        s2 = quad_allreduce(s2);
        s3 = quad_allreduce(s3);

        const float s01 = (qq & 1) ? s1 : s0;
        const float s23 = (qq & 1) ? s3 : s2;
        const float gs  = ((qq & 2) ? s23 : s01) + bias_own;
        const float av  = (qq == 2) ? tanh_f(gs) : sigm(gs);
        const float ai  = dpp_mov<0x00>(av);
        const float af  = dpp_mov<0x55>(av);
        const float ag  = dpp_mov<0xAA>(av);
        const float ao  = dpp_mov<0xFF>(av);

        const float dm = smask[t];
        const float cn = af * (c_reg * dm) + ai * ag;
        c_reg = cn;
        const float hn = ao * tanh_f(cn);

        if (qq == 0) {
            const float smn = smask[(t + 1 < T_STEPS) ? (t + 1) : (T_STEPS - 1)];
            reinterpret_cast<_Float16*>(h16[wb])[j] = (_Float16)(hn * smn);
            hs[((size_t)t * B_ENV + b) * H_DIM + j] = hn;
        }
        sync_lds();
    }
}

// ---------------------------------------------------------------------------
// In-place row projection: out[r,:] = out_row @ W_hid^T + b_hid.
#define PADK 68
__global__ __launch_bounds__(256)
void ppo_proj(const float* __restrict__ W_hid,   // [H,H]
              const float* __restrict__ b_hid,   // [H]
              float* __restrict__ out)           // [T*B, H] in-place
{
    __shared__ h2v wl[H_DIM][PADK];
    __shared__ h2v hl[H_DIM][PADK];
    const int tid = threadIdx.x;
    const int rg  = tid >> 4;
    const int cg  = tid & 15;

    const size_t r0 = (size_t)blockIdx.x * H_DIM;

    #pragma unroll
    for (int i = 0; i < 16; ++i) {
        const int idx = tid + 256 * i;
        const int r = idx >> 5, cc = idx & 31;
        f4v v = *reinterpret_cast<const f4v*>(W_hid + 4 * (size_t)idx);
        wl[r][2 * cc]     = pack16(v.x, v.y);
        wl[r][2 * cc + 1] = pack16(v.z, v.w);
    }
    #pragma unroll
    for (int i = 0; i < 16; ++i) {
        const int idx = tid + 256 * i;
        const int r = idx >> 5, cc = idx & 31;
        f4v v = *reinterpret_cast<const f4v*>(out + (r0 + r) * H_DIM + 4 * cc);
        hl[r][2 * cc]     = pack16(v.x, v.y);
        hl[r][2 * cc + 1] = pack16(v.z, v.w);
    }
    float bcol[8];
    #pragma unroll
    for (int jj = 0; jj < 8; ++jj) bcol[jj] = b_hid[cg + 16 * jj];
    __syncthreads();

    float acc[8][8];
    #pragma unroll
    for (int i = 0; i < 8; ++i)
        #pragma unroll
        for (int jj = 0; jj < 8; ++jj) acc[i][jj] = 0.f;

    for (int kq = 0; kq < 16; ++kq) {
        union { h8v v; h2v p[4]; } hv[8], wv[8];
        #pragma unroll
        for (int i = 0; i < 8; ++i)
            hv[i].v = *reinterpret_cast<const h8v*>(&hl[rg * 8 + i][4 * kq]);
        #pragma unroll
        for (int jj = 0; jj < 8; ++jj)
            wv[jj].v = *reinterpret_cast<const h8v*>(&wl[cg + 16 * jj][4 * kq]);
        #pragma unroll
        for (int i = 0; i < 8; ++i)
            #pragma unroll
            for (int jj = 0; jj < 8; ++jj) {
                acc[i][jj] = dot2(hv[i].p[0], wv[jj].p[0], acc[i][jj]);
                acc[i][jj] = dot2(hv[i].p[1], wv[jj].p[1], acc[i][jj]);
                acc[i][jj] = dot2(hv[i].p[2], wv[jj].p[2], acc[i][jj]);
                acc[i][jj] = dot2(hv[i].p[3], wv[jj].p[3], acc[i][jj]);
            }
    }

    #pragma unroll
    for (int i = 0; i < 8; ++i)
        #pragma unroll
        for (int jj = 0; jj < 8; ++jj)
            out[(r0 + rg * 8 + i) * H_DIM + cg + 16 * jj] = acc[i][jj] + bcol[jj];
}

extern "C" void kernel_launch(void* const* d_in, const int* in_sizes, int n_in,
                              void* d_out, int out_size, void* d_ws, size_t ws_size,
                              hipStream_t stream) {
    const float* x     = (const float*)d_in[0];
    const float* done  = (const float*)d_in[1];
    const float* h0    = (const float*)d_in[2];
    const float* c0    = (const float*)d_in[3];
    const float* W_ih  = (const float*)d_in[4];
    const float* b_ih  = (const float*)d_in[5];
    const float* W_hh  = (const float*)d_in[6];
    const float* b_hh  = (const float*)d_in[7];
    const float* W_hid = (const float*)d_in[8];
    const float* b_hid = (const float*)d_in[9];
    float* out = (float*)d_out;
    (void)n_in; (void)in_sizes; (void)out_size;

    const size_t xg_bytes = (size_t)T_STEPS * B_ENV * G4 * sizeof(unsigned short);
    if (ws_size >= xg_bytes) {
        unsigned short* xg = (unsigned short*)d_ws;
        hipLaunchKernelGGL(ppo_xg, dim3((T_STEPS * B_ENV) / 64), dim3(256), 0, stream,
                           x, W_ih, xg);
        hipLaunchKernelGGL(ppo_lstm_scan_xg, dim3(B_ENV), dim3(512), 0, stream,
                           xg, done, h0, c0, b_ih, W_hh, b_hh, out);
    } else {
        hipLaunchKernelGGL(ppo_lstm_scan_fb, dim3(B_ENV), dim3(512), 0, stream,
                           x, done, h0, c0, W_ih, b_ih, W_hh, b_hh, out);
    }
    hipLaunchKernelGGL(ppo_proj, dim3((T_STEPS * B_ENV) / H_DIM), dim3(256), 0, stream,
                       W_hid, b_hid, out);
}